// Round 1
// baseline (1785.071 us; speedup 1.0000x reference)
//
#include <hip/hip_runtime.h>
#include <cstdint>
#include <cmath>

// HashEncoderHyFluid: 4D multires hash-grid encode.
// thread = query; serial loop over 16 scales (soft L2 phasing);
// LDS transpose for coalesced output stores.

#define NSCALES 16
#define TPB 256

struct Cfg {
  float    res[NSCALES][4];     // per-scale grid resolution (float)
  uint32_t key[NSCALES][4];     // dense: strides; hashed: primes
  uint32_t mask[NSCALES];       // size-1 (pow2 for hashed scales)
  int      offset[NSCALES];     // element offset into hash table
  int      dense[NSCALES];      // indicator
};

typedef float v4f __attribute__((ext_vector_type(4)));

__global__ __launch_bounds__(TPB) void hashenc_kernel(
    const float4* __restrict__ xyzt,
    const float*  __restrict__ table,
    float*        __restrict__ out,
    int N, Cfg cfg)
{
  // +1 pad on inner dim to break bank alignment in the transpose reads
  __shared__ float2 st[NSCALES][TPB + 1];

  const int t  = threadIdx.x;
  const int q  = blockIdx.x * TPB + t;
  const int ql = q < N ? q : N - 1;
  const float4 c = xyzt[ql];

#pragma unroll 1   // keep scales temporally separated (L2 residency) + small code
  for (int s = 0; s < NSCALES; ++s) {
    const float rx = cfg.res[s][0], ry = cfg.res[s][1];
    const float rz = cfg.res[s][2], rw = cfg.res[s][3];
    const uint32_t K0 = cfg.key[s][0], K1 = cfg.key[s][1];
    const uint32_t K2 = cfg.key[s][2], K3 = cfg.key[s][3];

    // pos/grid/frac exactly as reference (single f32 mul, floorf, sub)
    const float px = c.x * rx, py = c.y * ry, pz = c.z * rz, pw = c.w * rw;
    const float gx = floorf(px), gy = floorf(py), gz = floorf(pz), gw = floorf(pw);
    const float fx = px - gx, fy = py - gy, fz = pz - gz, fw = pw - gw;
    const uint32_t ix = (uint32_t)(int)gx, iy = (uint32_t)(int)gy;
    const uint32_t iz = (uint32_t)(int)gz, iw = (uint32_t)(int)gw;

    // per-dim low/high key products (u32 wrap == numpy uint32 semantics)
    const uint32_t x0 = ix * K0, x1 = x0 + K0;
    const uint32_t y0 = iy * K1, y1 = y0 + K1;
    const uint32_t z0 = iz * K2, z1 = z0 + K2;
    const uint32_t u0 = iw * K3, u1 = u0 + K3;

    const float wx0 = 1.f - fx, wy0 = 1.f - fy, wz0 = 1.f - fz, ww0 = 1.f - fw;

    // pairwise combos: A = dims(0,1) indexed by b0+2*b1, B = dims(2,3) by b2+2*b3
    const float wA[4] = { wx0 * wy0, fx * wy0, wx0 * fy, fx * fy };
    const float wB[4] = { wz0 * ww0, fz * ww0, wz0 * fw, fz * fw };

    const float2* __restrict__ tb =
        reinterpret_cast<const float2*>(table + cfg.offset[s]);

    float a0 = 0.f, a1 = 0.f;
    if (cfg.dense[s]) {
      // dense: linear index, provably < size (no mod needed)
      const uint32_t hA[4] = { x0 + y0, x1 + y0, x0 + y1, x1 + y1 };
      const uint32_t hB[4] = { z0 + u0, z1 + u0, z0 + u1, z1 + u1 };
#pragma unroll
      for (int i = 0; i < 16; ++i) {
        const uint32_t idx = hA[i & 3] + hB[i >> 2];
        const float2 v = tb[idx];
        const float w = wA[i & 3] * wB[i >> 2];
        a0 = fmaf(w, v.x, a0);
        a1 = fmaf(w, v.y, a1);
      }
    } else {
      // hashed: xor of prime products, size is pow2 -> mask
      const uint32_t msk = cfg.mask[s];
      const uint32_t hA[4] = { x0 ^ y0, x1 ^ y0, x0 ^ y1, x1 ^ y1 };
      const uint32_t hB[4] = { z0 ^ u0, z1 ^ u0, z0 ^ u1, z1 ^ u1 };
#pragma unroll
      for (int i = 0; i < 16; ++i) {
        const uint32_t idx = (hA[i & 3] ^ hB[i >> 2]) & msk;
        const float2 v = tb[idx];
        const float w = wA[i & 3] * wB[i >> 2];
        a0 = fmaf(w, v.x, a0);
        a1 = fmaf(w, v.y, a1);
      }
    }
    st[s][t] = make_float2(a0, a1);
  }

  __syncthreads();

  // coalesced write-out: block covers TPB*32 floats contiguous
  const int base = blockIdx.x * (TPB * 2 * NSCALES);
#pragma unroll
  for (int it = 0; it < 8; ++it) {
    const int G  = it * 1024 + t * 4;   // float index within block's slab
    const int qi = G >> 5;              // local query
    const int s0 = (G & 31) >> 1;       // scale of first pair (even)
    if (blockIdx.x * TPB + qi < N) {
      const float2 a = st[s0][qi];
      const float2 b = st[s0 + 1][qi];
      v4f val = { a.x, a.y, b.x, b.y };
      __builtin_nontemporal_store(val, (v4f*)(out + base + G));
    }
  }
}

// ---- host-side config, bit-exact replication of build_config() ----
static void build_cfg(Cfg& cfg)
{
  const double minr[4] = { 16.0, 16.0, 16.0, 16.0 };
  const double maxr[4] = { 256.0, 256.0, 256.0, 128.0 };
  const uint32_t primes[4] = { 1u, 2654435761u, 805459861u, 3674653429u };

  double b[4];
  for (int d = 0; d < 4; ++d)
    b[d] = ::exp((::log(maxr[d]) - ::log(minr[d])) / (double)(NSCALES - 1));

  long long total = 0;
  for (int s = 0; s < NSCALES; ++s) {
    long long res[4];
    for (int d = 0; d < 4; ++d)
      res[d] = (long long)::ceil(minr[d] * ::pow(b[d], (double)s));

    const long long raw =
        (res[0] + 1) * (res[1] + 1) * (res[2] + 1) * (res[3] + 1);
    long long p = (raw % 8 == 0) ? raw : ((raw + 7) / 8) * 8;
    if (p > 524288) p = 524288;
    const int ind = (raw <= p) ? 1 : 0;

    for (int d = 0; d < 4; ++d) cfg.res[s][d] = (float)res[d];
    if (ind) {
      cfg.key[s][0] = 1u;
      cfg.key[s][1] = (uint32_t)(res[0] + 1);
      cfg.key[s][2] = (uint32_t)((res[0] + 1) * (res[1] + 1));
      cfg.key[s][3] = (uint32_t)((res[0] + 1) * (res[1] + 1) * (res[2] + 1));
    } else {
      for (int d = 0; d < 4; ++d) cfg.key[s][d] = primes[d];
    }
    cfg.mask[s]   = (uint32_t)(p - 1);
    cfg.offset[s] = (int)total;
    cfg.dense[s]  = ind;
    total += p * 2;
  }
}

extern "C" void kernel_launch(void* const* d_in, const int* in_sizes, int n_in,
                              void* d_out, int out_size, void* d_ws, size_t ws_size,
                              hipStream_t stream)
{
  const float4* xyzt  = (const float4*)d_in[0];
  const float*  table = (const float*)d_in[1];
  float*        out   = (float*)d_out;
  const int N = in_sizes[0] / 4;

  Cfg cfg;
  build_cfg(cfg);

  const int blocks = (N + TPB - 1) / TPB;
  hipLaunchKernelGGL(hashenc_kernel, dim3(blocks), dim3(TPB), 0, stream,
                     xyzt, table, out, N, cfg);
}

// Round 2
// 951.765 us; speedup vs baseline: 1.8755x; 1.8755x over previous
//
#include <hip/hip_runtime.h>
#include <cstdint>
#include <cmath>

// HashEncoderHyFluid round 2: scale-major two-phase.
// Phase 1 (gather): grid=(qblocks, 16); blockIdx.y = scale is the SLOW grid
//   dim -> all blocks of scale s dispatch before s+1 -> one ~4MB table live
//   per XCD L2 at a time (round 1's fused loop thrashed ~5 tables).
//   No LDS -> full occupancy for gather latency hiding.
//   Writes scale-major float2 to d_ws (coalesced, nontemporal).
// Phase 2 (transpose): ws[s][q] -> out[q][2s..2s+1] via LDS, 16B nt stores.

#define NSCALES 16
#define TPB 256

struct Cfg {
  float    res[NSCALES][4];
  uint32_t key[NSCALES][4];
  uint32_t mask[NSCALES];
  int      offset[NSCALES];
  int      dense[NSCALES];
};

typedef float v4f __attribute__((ext_vector_type(4)));
typedef float v2f __attribute__((ext_vector_type(2)));

// ---------------- phase 1: per-scale gather ----------------
__global__ __launch_bounds__(TPB) void gather_kernel(
    const float4* __restrict__ xyzt,
    const float*  __restrict__ table,
    float2*       __restrict__ ws,
    int N, Cfg cfg)
{
  const int s = blockIdx.y;
  const int q = blockIdx.x * TPB + threadIdx.x;
  if (q >= N) return;
  const float4 c = xyzt[q];

  const float rx = cfg.res[s][0], ry = cfg.res[s][1];
  const float rz = cfg.res[s][2], rw = cfg.res[s][3];
  const uint32_t K0 = cfg.key[s][0], K1 = cfg.key[s][1];
  const uint32_t K2 = cfg.key[s][2], K3 = cfg.key[s][3];

  const float px = c.x * rx, py = c.y * ry, pz = c.z * rz, pw = c.w * rw;
  const float gx = floorf(px), gy = floorf(py), gz = floorf(pz), gw = floorf(pw);
  const float fx = px - gx, fy = py - gy, fz = pz - gz, fw = pw - gw;
  const uint32_t ix = (uint32_t)(int)gx, iy = (uint32_t)(int)gy;
  const uint32_t iz = (uint32_t)(int)gz, iw = (uint32_t)(int)gw;

  const uint32_t x0 = ix * K0, x1 = x0 + K0;
  const uint32_t y0 = iy * K1, y1 = y0 + K1;
  const uint32_t z0 = iz * K2, z1 = z0 + K2;
  const uint32_t u0 = iw * K3, u1 = u0 + K3;

  const float wx0 = 1.f - fx, wy0 = 1.f - fy, wz0 = 1.f - fz, ww0 = 1.f - fw;
  const float wA[4] = { wx0 * wy0, fx * wy0, wx0 * fy, fx * fy };
  const float wB[4] = { wz0 * ww0, fz * ww0, wz0 * fw, fz * fw };

  const float2* __restrict__ tb =
      reinterpret_cast<const float2*>(table + cfg.offset[s]);

  float a0 = 0.f, a1 = 0.f;
  if (cfg.dense[s]) {
    const uint32_t hA[4] = { x0 + y0, x1 + y0, x0 + y1, x1 + y1 };
    const uint32_t hB[4] = { z0 + u0, z1 + u0, z0 + u1, z1 + u1 };
#pragma unroll
    for (int i = 0; i < 16; ++i) {
      const uint32_t idx = hA[i & 3] + hB[i >> 2];
      const float2 v = tb[idx];
      const float w = wA[i & 3] * wB[i >> 2];
      a0 = fmaf(w, v.x, a0);
      a1 = fmaf(w, v.y, a1);
    }
  } else {
    const uint32_t msk = cfg.mask[s];
    const uint32_t hA[4] = { x0 ^ y0, x1 ^ y0, x0 ^ y1, x1 ^ y1 };
    const uint32_t hB[4] = { z0 ^ u0, z1 ^ u0, z0 ^ u1, z1 ^ u1 };
#pragma unroll
    for (int i = 0; i < 16; ++i) {
      const uint32_t idx = (hA[i & 3] ^ hB[i >> 2]) & msk;
      const float2 v = tb[idx];
      const float w = wA[i & 3] * wB[i >> 2];
      a0 = fmaf(w, v.x, a0);
      a1 = fmaf(w, v.y, a1);
    }
  }
  v2f val = { a0, a1 };
  __builtin_nontemporal_store(val, (v2f*)&ws[(size_t)s * N + q]);
}

// ---------------- phase 2: scale-major -> query-major transpose ----------------
__global__ __launch_bounds__(TPB) void transpose_kernel(
    const float2* __restrict__ ws,
    float*        __restrict__ out,
    int N)
{
  __shared__ float2 st[NSCALES][TPB + 1];
  const int t  = threadIdx.x;
  const int q  = blockIdx.x * TPB + t;
  const int ql = q < N ? q : N - 1;

#pragma unroll
  for (int s = 0; s < NSCALES; ++s)
    st[s][t] = ws[(size_t)s * N + ql];

  __syncthreads();

  const int base = blockIdx.x * (TPB * 2 * NSCALES);
#pragma unroll
  for (int it = 0; it < 8; ++it) {
    const int G  = it * 1024 + t * 4;
    const int qi = G >> 5;
    const int s0 = (G & 31) >> 1;
    if (blockIdx.x * TPB + qi < N) {
      const float2 a = st[s0][qi];
      const float2 b = st[s0 + 1][qi];
      v4f val = { a.x, a.y, b.x, b.y };
      __builtin_nontemporal_store(val, (v4f*)(out + base + G));
    }
  }
}

// ---------------- fallback: round-1 fused kernel (if ws too small) ----------------
__global__ __launch_bounds__(TPB) void hashenc_fused(
    const float4* __restrict__ xyzt,
    const float*  __restrict__ table,
    float*        __restrict__ out,
    int N, Cfg cfg)
{
  __shared__ float2 st[NSCALES][TPB + 1];
  const int t  = threadIdx.x;
  const int q  = blockIdx.x * TPB + t;
  const int ql = q < N ? q : N - 1;
  const float4 c = xyzt[ql];

#pragma unroll 1
  for (int s = 0; s < NSCALES; ++s) {
    const float rx = cfg.res[s][0], ry = cfg.res[s][1];
    const float rz = cfg.res[s][2], rw = cfg.res[s][3];
    const uint32_t K0 = cfg.key[s][0], K1 = cfg.key[s][1];
    const uint32_t K2 = cfg.key[s][2], K3 = cfg.key[s][3];
    const float px = c.x * rx, py = c.y * ry, pz = c.z * rz, pw = c.w * rw;
    const float gx = floorf(px), gy = floorf(py), gz = floorf(pz), gw = floorf(pw);
    const float fx = px - gx, fy = py - gy, fz = pz - gz, fw = pw - gw;
    const uint32_t ix = (uint32_t)(int)gx, iy = (uint32_t)(int)gy;
    const uint32_t iz = (uint32_t)(int)gz, iw = (uint32_t)(int)gw;
    const uint32_t x0 = ix * K0, x1 = x0 + K0;
    const uint32_t y0 = iy * K1, y1 = y0 + K1;
    const uint32_t z0 = iz * K2, z1 = z0 + K2;
    const uint32_t u0 = iw * K3, u1 = u0 + K3;
    const float wx0 = 1.f - fx, wy0 = 1.f - fy, wz0 = 1.f - fz, ww0 = 1.f - fw;
    const float wA[4] = { wx0 * wy0, fx * wy0, wx0 * fy, fx * fy };
    const float wB[4] = { wz0 * ww0, fz * ww0, wz0 * fw, fz * fw };
    const float2* __restrict__ tb =
        reinterpret_cast<const float2*>(table + cfg.offset[s]);
    float a0 = 0.f, a1 = 0.f;
    if (cfg.dense[s]) {
      const uint32_t hA[4] = { x0 + y0, x1 + y0, x0 + y1, x1 + y1 };
      const uint32_t hB[4] = { z0 + u0, z1 + u0, z0 + u1, z1 + u1 };
#pragma unroll
      for (int i = 0; i < 16; ++i) {
        const uint32_t idx = hA[i & 3] + hB[i >> 2];
        const float2 v = tb[idx];
        const float w = wA[i & 3] * wB[i >> 2];
        a0 = fmaf(w, v.x, a0); a1 = fmaf(w, v.y, a1);
      }
    } else {
      const uint32_t msk = cfg.mask[s];
      const uint32_t hA[4] = { x0 ^ y0, x1 ^ y0, x0 ^ y1, x1 ^ y1 };
      const uint32_t hB[4] = { z0 ^ u0, z1 ^ u0, z0 ^ u1, z1 ^ u1 };
#pragma unroll
      for (int i = 0; i < 16; ++i) {
        const uint32_t idx = (hA[i & 3] ^ hB[i >> 2]) & msk;
        const float2 v = tb[idx];
        const float w = wA[i & 3] * wB[i >> 2];
        a0 = fmaf(w, v.x, a0); a1 = fmaf(w, v.y, a1);
      }
    }
    st[s][t] = make_float2(a0, a1);
  }
  __syncthreads();
  const int base = blockIdx.x * (TPB * 2 * NSCALES);
#pragma unroll
  for (int it = 0; it < 8; ++it) {
    const int G  = it * 1024 + t * 4;
    const int qi = G >> 5;
    const int s0 = (G & 31) >> 1;
    if (blockIdx.x * TPB + qi < N) {
      const float2 a = st[s0][qi];
      const float2 b = st[s0 + 1][qi];
      v4f val = { a.x, a.y, b.x, b.y };
      __builtin_nontemporal_store(val, (v4f*)(out + base + G));
    }
  }
}

// ---- host-side config, bit-exact replication of build_config() ----
static void build_cfg(Cfg& cfg)
{
  const double minr[4] = { 16.0, 16.0, 16.0, 16.0 };
  const double maxr[4] = { 256.0, 256.0, 256.0, 128.0 };
  const uint32_t primes[4] = { 1u, 2654435761u, 805459861u, 3674653429u };

  double b[4];
  for (int d = 0; d < 4; ++d)
    b[d] = ::exp((::log(maxr[d]) - ::log(minr[d])) / (double)(NSCALES - 1));

  long long total = 0;
  for (int s = 0; s < NSCALES; ++s) {
    long long res[4];
    for (int d = 0; d < 4; ++d)
      res[d] = (long long)::ceil(minr[d] * ::pow(b[d], (double)s));

    const long long raw =
        (res[0] + 1) * (res[1] + 1) * (res[2] + 1) * (res[3] + 1);
    long long p = (raw % 8 == 0) ? raw : ((raw + 7) / 8) * 8;
    if (p > 524288) p = 524288;
    const int ind = (raw <= p) ? 1 : 0;

    for (int d = 0; d < 4; ++d) cfg.res[s][d] = (float)res[d];
    if (ind) {
      cfg.key[s][0] = 1u;
      cfg.key[s][1] = (uint32_t)(res[0] + 1);
      cfg.key[s][2] = (uint32_t)((res[0] + 1) * (res[1] + 1));
      cfg.key[s][3] = (uint32_t)((res[0] + 1) * (res[1] + 1) * (res[2] + 1));
    } else {
      for (int d = 0; d < 4; ++d) cfg.key[s][d] = primes[d];
    }
    cfg.mask[s]   = (uint32_t)(p - 1);
    cfg.offset[s] = (int)total;
    cfg.dense[s]  = ind;
    total += p * 2;
  }
}

extern "C" void kernel_launch(void* const* d_in, const int* in_sizes, int n_in,
                              void* d_out, int out_size, void* d_ws, size_t ws_size,
                              hipStream_t stream)
{
  const float4* xyzt  = (const float4*)d_in[0];
  const float*  table = (const float*)d_in[1];
  float*        out   = (float*)d_out;
  const int N = in_sizes[0] / 4;

  Cfg cfg;
  build_cfg(cfg);

  const int qblocks = (N + TPB - 1) / TPB;
  const size_t need = (size_t)N * NSCALES * sizeof(float2);

  if (ws_size >= need) {
    float2* ws = (float2*)d_ws;
    hipLaunchKernelGGL(gather_kernel, dim3(qblocks, NSCALES), dim3(TPB), 0,
                       stream, xyzt, table, ws, N, cfg);
    hipLaunchKernelGGL(transpose_kernel, dim3(qblocks), dim3(TPB), 0,
                       stream, ws, out, N);
  } else {
    hipLaunchKernelGGL(hashenc_fused, dim3(qblocks), dim3(TPB), 0,
                       stream, xyzt, table, out, N, cfg);
  }
}

// Round 4
// 876.827 us; speedup vs baseline: 2.0358x; 1.0855x over previous
//
#include <hip/hip_runtime.h>
#include <cstdint>
#include <cmath>

// HashEncoderHyFluid round 4 (= round 3 with compile fix: nontemporal load
// via clang-native ext_vector type, not HIP_vector_type).
// Phase 1 (gather): grid=(qblocks, 16 scales), scale = slow grid dim (L2
//   phasing, round-2 verified: FETCH 6.2GB -> 715MB). For hashed scales,
//   PRIMES[0]==1 means x-corner pairs hash to {p, p^1} when ix is even ->
//   one aligned float4 load covers both corners: 8 requests instead of 16
//   for ~50% of lanes. Request throughput is the measured limiter
//   (0.54 line-lookups/cycle/CU, HBM 14%, VALU 6%).
// Phase 2 (transpose): ws[s][q] -> out[q][2s..2s+1] via LDS (unchanged).

#define NSCALES 16
#define TPB 256

struct Cfg {
  float    res[NSCALES][4];
  uint32_t key[NSCALES][4];
  uint32_t mask[NSCALES];
  int      offset[NSCALES];
  int      dense[NSCALES];
};

typedef float v4f __attribute__((ext_vector_type(4)));
typedef float v2f __attribute__((ext_vector_type(2)));

// ---------------- phase 1: per-scale gather ----------------
__global__ __launch_bounds__(TPB) void gather_kernel(
    const float*  __restrict__ xyzt,
    const float*  __restrict__ table,
    float2*       __restrict__ ws,
    int N, Cfg cfg)
{
  const int s = blockIdx.y;
  const int q = blockIdx.x * TPB + threadIdx.x;
  if (q >= N) return;
  // nt load: coord stream shouldn't evict table lines from L2
  const v4f c = __builtin_nontemporal_load(
      reinterpret_cast<const v4f*>(xyzt) + q);

  const float rx = cfg.res[s][0], ry = cfg.res[s][1];
  const float rz = cfg.res[s][2], rw = cfg.res[s][3];
  const uint32_t K0 = cfg.key[s][0], K1 = cfg.key[s][1];
  const uint32_t K2 = cfg.key[s][2], K3 = cfg.key[s][3];

  const float px = c.x * rx, py = c.y * ry, pz = c.z * rz, pw = c.w * rw;
  const float gx = floorf(px), gy = floorf(py), gz = floorf(pz), gw = floorf(pw);
  const float fx = px - gx, fy = py - gy, fz = pz - gz, fw = pw - gw;
  const uint32_t ix = (uint32_t)(int)gx, iy = (uint32_t)(int)gy;
  const uint32_t iz = (uint32_t)(int)gz, iw = (uint32_t)(int)gw;

  const uint32_t x0 = ix * K0, x1 = x0 + K0;
  const uint32_t y0 = iy * K1, y1 = y0 + K1;
  const uint32_t z0 = iz * K2, z1 = z0 + K2;
  const uint32_t u0 = iw * K3, u1 = u0 + K3;

  const float wx0 = 1.f - fx, wy0 = 1.f - fy, wz0 = 1.f - fz, ww0 = 1.f - fw;
  const float wA[4] = { wx0 * wy0, fx * wy0, wx0 * fy, fx * fy };
  const float wB[4] = { wz0 * ww0, fz * ww0, wz0 * fw, fz * fw };

  const float*  tbf = table + cfg.offset[s];
  const float2* __restrict__ tb  = reinterpret_cast<const float2*>(tbf);
  const float4* __restrict__ tb4 = reinterpret_cast<const float4*>(tbf);

  float a0 = 0.f, a1 = 0.f;
  if (cfg.dense[s]) {
    const uint32_t hA[4] = { x0 + y0, x1 + y0, x0 + y1, x1 + y1 };
    const uint32_t hB[4] = { z0 + u0, z1 + u0, z0 + u1, z1 + u1 };
#pragma unroll
    for (int i = 0; i < 16; ++i) {
      const uint32_t idx = hA[i & 3] + hB[i >> 2];
      const float2 v = tb[idx];
      const float w = wA[i & 3] * wB[i >> 2];
      a0 = fmaf(w, v.x, a0);
      a1 = fmaf(w, v.y, a1);
    }
  } else {
    const uint32_t msk = cfg.mask[s];
    if ((ix & 1u) == 0u) {
      // even ix: x-corner pair = {p, p^1} -> one aligned float4 each
      const uint32_t yv[2] = { y0, y1 };
      const uint32_t zw[4] = { z0 ^ u0, z1 ^ u0, z0 ^ u1, z1 ^ u1 };
#pragma unroll
      for (int j = 0; j < 8; ++j) {
        const int jy = j & 1, jz = j >> 1;
        const uint32_t p  = (x0 ^ yv[jy] ^ zw[jz]) & msk;
        const uint32_t e  = p & ~1u;          // even element: 16B aligned
        const uint32_t sel = p & 1u;          // which half is the x-lo corner
        const float4 v = tb4[e >> 1];
        const float wlo = wA[2 * jy]     * wB[jz];
        const float whi = wA[2 * jy + 1] * wB[jz];
        const float l0 = sel ? v.z : v.x, l1 = sel ? v.w : v.y;
        const float h0 = sel ? v.x : v.z, h1 = sel ? v.y : v.w;
        a0 = fmaf(wlo, l0, fmaf(whi, h0, a0));
        a1 = fmaf(wlo, l1, fmaf(whi, h1, a1));
      }
    } else {
      const uint32_t hA[4] = { x0 ^ y0, x1 ^ y0, x0 ^ y1, x1 ^ y1 };
      const uint32_t hB[4] = { z0 ^ u0, z1 ^ u0, z0 ^ u1, z1 ^ u1 };
#pragma unroll
      for (int i = 0; i < 16; ++i) {
        const uint32_t idx = (hA[i & 3] ^ hB[i >> 2]) & msk;
        const float2 v = tb[idx];
        const float w = wA[i & 3] * wB[i >> 2];
        a0 = fmaf(w, v.x, a0);
        a1 = fmaf(w, v.y, a1);
      }
    }
  }
  v2f val = { a0, a1 };
  __builtin_nontemporal_store(val, (v2f*)&ws[(size_t)s * N + q]);
}

// ---------------- phase 2: scale-major -> query-major transpose ----------------
__global__ __launch_bounds__(TPB) void transpose_kernel(
    const float2* __restrict__ ws,
    float*        __restrict__ out,
    int N)
{
  __shared__ float2 st[NSCALES][TPB + 1];
  const int t  = threadIdx.x;
  const int q  = blockIdx.x * TPB + t;
  const int ql = q < N ? q : N - 1;

#pragma unroll
  for (int s = 0; s < NSCALES; ++s)
    st[s][t] = ws[(size_t)s * N + ql];

  __syncthreads();

  const int base = blockIdx.x * (TPB * 2 * NSCALES);
#pragma unroll
  for (int it = 0; it < 8; ++it) {
    const int G  = it * 1024 + t * 4;
    const int qi = G >> 5;
    const int s0 = (G & 31) >> 1;
    if (blockIdx.x * TPB + qi < N) {
      const float2 a = st[s0][qi];
      const float2 b = st[s0 + 1][qi];
      v4f val = { a.x, a.y, b.x, b.y };
      __builtin_nontemporal_store(val, (v4f*)(out + base + G));
    }
  }
}

// ---------------- fallback: fused single-kernel (if ws too small) ----------------
__global__ __launch_bounds__(TPB) void hashenc_fused(
    const float4* __restrict__ xyzt,
    const float*  __restrict__ table,
    float*        __restrict__ out,
    int N, Cfg cfg)
{
  __shared__ float2 st[NSCALES][TPB + 1];
  const int t  = threadIdx.x;
  const int q  = blockIdx.x * TPB + t;
  const int ql = q < N ? q : N - 1;
  const float4 c = xyzt[ql];

#pragma unroll 1
  for (int s = 0; s < NSCALES; ++s) {
    const float rx = cfg.res[s][0], ry = cfg.res[s][1];
    const float rz = cfg.res[s][2], rw = cfg.res[s][3];
    const uint32_t K0 = cfg.key[s][0], K1 = cfg.key[s][1];
    const uint32_t K2 = cfg.key[s][2], K3 = cfg.key[s][3];
    const float px = c.x * rx, py = c.y * ry, pz = c.z * rz, pw = c.w * rw;
    const float gx = floorf(px), gy = floorf(py), gz = floorf(pz), gw = floorf(pw);
    const float fx = px - gx, fy = py - gy, fz = pz - gz, fw = pw - gw;
    const uint32_t ix = (uint32_t)(int)gx, iy = (uint32_t)(int)gy;
    const uint32_t iz = (uint32_t)(int)gz, iw = (uint32_t)(int)gw;
    const uint32_t x0 = ix * K0, x1 = x0 + K0;
    const uint32_t y0 = iy * K1, y1 = y0 + K1;
    const uint32_t z0 = iz * K2, z1 = z0 + K2;
    const uint32_t u0 = iw * K3, u1 = u0 + K3;
    const float wx0 = 1.f - fx, wy0 = 1.f - fy, wz0 = 1.f - fz, ww0 = 1.f - fw;
    const float wA[4] = { wx0 * wy0, fx * wy0, wx0 * fy, fx * fy };
    const float wB[4] = { wz0 * ww0, fz * ww0, wz0 * fw, fz * fw };
    const float2* __restrict__ tb =
        reinterpret_cast<const float2*>(table + cfg.offset[s]);
    float a0 = 0.f, a1 = 0.f;
    if (cfg.dense[s]) {
      const uint32_t hA[4] = { x0 + y0, x1 + y0, x0 + y1, x1 + y1 };
      const uint32_t hB[4] = { z0 + u0, z1 + u0, z0 + u1, z1 + u1 };
#pragma unroll
      for (int i = 0; i < 16; ++i) {
        const uint32_t idx = hA[i & 3] + hB[i >> 2];
        const float2 v = tb[idx];
        const float w = wA[i & 3] * wB[i >> 2];
        a0 = fmaf(w, v.x, a0); a1 = fmaf(w, v.y, a1);
      }
    } else {
      const uint32_t msk = cfg.mask[s];
      const uint32_t hA[4] = { x0 ^ y0, x1 ^ y0, x0 ^ y1, x1 ^ y1 };
      const uint32_t hB[4] = { z0 ^ u0, z1 ^ u0, z0 ^ u1, z1 ^ u1 };
#pragma unroll
      for (int i = 0; i < 16; ++i) {
        const uint32_t idx = (hA[i & 3] ^ hB[i >> 2]) & msk;
        const float2 v = tb[idx];
        const float w = wA[i & 3] * wB[i >> 2];
        a0 = fmaf(w, v.x, a0); a1 = fmaf(w, v.y, a1);
      }
    }
    st[s][t] = make_float2(a0, a1);
  }
  __syncthreads();
  const int base = blockIdx.x * (TPB * 2 * NSCALES);
#pragma unroll
  for (int it = 0; it < 8; ++it) {
    const int G  = it * 1024 + t * 4;
    const int qi = G >> 5;
    const int s0 = (G & 31) >> 1;
    if (blockIdx.x * TPB + qi < N) {
      const float2 a = st[s0][qi];
      const float2 b = st[s0 + 1][qi];
      v4f val = { a.x, a.y, b.x, b.y };
      __builtin_nontemporal_store(val, (v4f*)(out + base + G));
    }
  }
}

// ---- host-side config, bit-exact replication of build_config() ----
static void build_cfg(Cfg& cfg)
{
  const double minr[4] = { 16.0, 16.0, 16.0, 16.0 };
  const double maxr[4] = { 256.0, 256.0, 256.0, 128.0 };
  const uint32_t primes[4] = { 1u, 2654435761u, 805459861u, 3674653429u };

  double b[4];
  for (int d = 0; d < 4; ++d)
    b[d] = ::exp((::log(maxr[d]) - ::log(minr[d])) / (double)(NSCALES - 1));

  long long total = 0;
  for (int s = 0; s < NSCALES; ++s) {
    long long res[4];
    for (int d = 0; d < 4; ++d)
      res[d] = (long long)::ceil(minr[d] * ::pow(b[d], (double)s));

    const long long raw =
        (res[0] + 1) * (res[1] + 1) * (res[2] + 1) * (res[3] + 1);
    long long p = (raw % 8 == 0) ? raw : ((raw + 7) / 8) * 8;
    if (p > 524288) p = 524288;
    const int ind = (raw <= p) ? 1 : 0;

    for (int d = 0; d < 4; ++d) cfg.res[s][d] = (float)res[d];
    if (ind) {
      cfg.key[s][0] = 1u;
      cfg.key[s][1] = (uint32_t)(res[0] + 1);
      cfg.key[s][2] = (uint32_t)((res[0] + 1) * (res[1] + 1));
      cfg.key[s][3] = (uint32_t)((res[0] + 1) * (res[1] + 1) * (res[2] + 1));
    } else {
      for (int d = 0; d < 4; ++d) cfg.key[s][d] = primes[d];
    }
    cfg.mask[s]   = (uint32_t)(p - 1);
    cfg.offset[s] = (int)total;
    cfg.dense[s]  = ind;
    total += p * 2;
  }
}

extern "C" void kernel_launch(void* const* d_in, const int* in_sizes, int n_in,
                              void* d_out, int out_size, void* d_ws, size_t ws_size,
                              hipStream_t stream)
{
  const float*  xyzt  = (const float*)d_in[0];
  const float*  table = (const float*)d_in[1];
  float*        out   = (float*)d_out;
  const int N = in_sizes[0] / 4;

  Cfg cfg;
  build_cfg(cfg);

  const int qblocks = (N + TPB - 1) / TPB;
  const size_t need = (size_t)N * NSCALES * sizeof(float2);

  if (ws_size >= need) {
    float2* ws = (float2*)d_ws;
    hipLaunchKernelGGL(gather_kernel, dim3(qblocks, NSCALES), dim3(TPB), 0,
                       stream, xyzt, table, ws, N, cfg);
    hipLaunchKernelGGL(transpose_kernel, dim3(qblocks), dim3(TPB), 0,
                       stream, ws, out, N);
  } else {
    hipLaunchKernelGGL(hashenc_fused, dim3(qblocks), dim3(TPB), 0,
                       stream, (const float4*)xyzt, table, out, N, cfg);
  }
}

// Round 5
// 835.592 us; speedup vs baseline: 2.1363x; 1.0493x over previous
//
#include <hip/hip_runtime.h>
#include <cstdint>
#include <cmath>

// HashEncoderHyFluid round 5: spatial bucket-sort + direct transpose.
// r4 analysis: gather is limited by unique-cache-line touches per VMEM
// instruction (~78 cyc/instr = ~64 unique lines x ~1.2 cyc). Random query
// order means zero line sharing between lanes. Fix: counting-sort queries
// into 65536 Morton buckets (16 bins/dim); sorted waves share corner cells
// at scales s<=6 (cells(s) ~= 65536*2^s vs 1M points).
// Pipeline: memset(hist,cur) -> histogram -> scan -> scatter(perm,c_sorted)
//        -> gather (scale-major phasing, even-ix float4 pairing, r2/r4)
//        -> direct transpose (no LDS, perm-scatter 128B/query output).

#define NSCALES 16
#define TPB 256
#define BINS 65536

struct Cfg {
  float    res[NSCALES][4];
  uint32_t key[NSCALES][4];
  uint32_t mask[NSCALES];
  int      offset[NSCALES];
  int      dense[NSCALES];
};

typedef float v4f __attribute__((ext_vector_type(4)));
typedef float v2f __attribute__((ext_vector_type(2)));

__device__ __forceinline__ uint32_t bucket_key(float x, float y, float z, float w)
{
  uint32_t bx = (uint32_t)(x * 16.f); bx = bx > 15u ? 15u : bx;
  uint32_t by = (uint32_t)(y * 16.f); by = by > 15u ? 15u : by;
  uint32_t bz = (uint32_t)(z * 16.f); bz = bz > 15u ? 15u : bz;
  uint32_t bt = (uint32_t)(w * 16.f); bt = bt > 15u ? 15u : bt;
  uint32_t k = 0;
#pragma unroll
  for (int b = 0; b < 4; ++b) {
    k |= ((bx >> b) & 1u) << (4 * b + 0);
    k |= ((by >> b) & 1u) << (4 * b + 1);
    k |= ((bz >> b) & 1u) << (4 * b + 2);
    k |= ((bt >> b) & 1u) << (4 * b + 3);
  }
  return k;
}

// ---------------- sort phase ----------------
__global__ __launch_bounds__(TPB) void hist_kernel(
    const float* __restrict__ xyzt, uint32_t* __restrict__ hist, int N)
{
  const int i = blockIdx.x * TPB + threadIdx.x;
  if (i >= N) return;
  const v4f c = *(reinterpret_cast<const v4f*>(xyzt) + i);
  atomicAdd(&hist[bucket_key(c.x, c.y, c.z, c.w)], 1u);
}

__global__ __launch_bounds__(256) void scan_kernel(
    const uint32_t* __restrict__ hist, uint32_t* __restrict__ boff)
{
  __shared__ uint32_t part[256];
  const int t = threadIdx.x;
  const int base = t * (BINS / 256);
  uint32_t s = 0;
  for (int j = 0; j < BINS / 256; ++j) s += hist[base + j];
  part[t] = s;
  __syncthreads();
  for (int off = 1; off < 256; off <<= 1) {
    uint32_t v = (t >= off) ? part[t - off] : 0u;
    __syncthreads();
    part[t] += v;
    __syncthreads();
  }
  uint32_t run = part[t] - s;   // exclusive prefix of this chunk
  for (int j = 0; j < BINS / 256; ++j) {
    boff[base + j] = run;
    run += hist[base + j];
  }
}

__global__ __launch_bounds__(TPB) void scatter_kernel(
    const float* __restrict__ xyzt,
    const uint32_t* __restrict__ boff, uint32_t* __restrict__ cur,
    uint32_t* __restrict__ perm, float* __restrict__ c_sorted, int N)
{
  const int i = blockIdx.x * TPB + threadIdx.x;
  if (i >= N) return;
  const v4f c = *(reinterpret_cast<const v4f*>(xyzt) + i);
  const uint32_t k = bucket_key(c.x, c.y, c.z, c.w);
  const uint32_t pos = boff[k] + atomicAdd(&cur[k], 1u);
  perm[pos] = (uint32_t)i;
  *(reinterpret_cast<v4f*>(c_sorted) + pos) = c;
}

// ---------------- gather: per-scale, scale = slow grid dim ----------------
__global__ __launch_bounds__(TPB) void gather_kernel(
    const float*  __restrict__ coords,
    const float*  __restrict__ table,
    float2*       __restrict__ ws,
    int N, Cfg cfg)
{
  const int s = blockIdx.y;
  const int q = blockIdx.x * TPB + threadIdx.x;
  if (q >= N) return;
  const v4f c = *(reinterpret_cast<const v4f*>(coords) + q);

  const float rx = cfg.res[s][0], ry = cfg.res[s][1];
  const float rz = cfg.res[s][2], rw = cfg.res[s][3];
  const uint32_t K0 = cfg.key[s][0], K1 = cfg.key[s][1];
  const uint32_t K2 = cfg.key[s][2], K3 = cfg.key[s][3];

  const float px = c.x * rx, py = c.y * ry, pz = c.z * rz, pw = c.w * rw;
  const float gx = floorf(px), gy = floorf(py), gz = floorf(pz), gw = floorf(pw);
  const float fx = px - gx, fy = py - gy, fz = pz - gz, fw = pw - gw;
  const uint32_t ix = (uint32_t)(int)gx, iy = (uint32_t)(int)gy;
  const uint32_t iz = (uint32_t)(int)gz, iw = (uint32_t)(int)gw;

  const uint32_t x0 = ix * K0, x1 = x0 + K0;
  const uint32_t y0 = iy * K1, y1 = y0 + K1;
  const uint32_t z0 = iz * K2, z1 = z0 + K2;
  const uint32_t u0 = iw * K3, u1 = u0 + K3;

  const float wx0 = 1.f - fx, wy0 = 1.f - fy, wz0 = 1.f - fz, ww0 = 1.f - fw;
  const float wA[4] = { wx0 * wy0, fx * wy0, wx0 * fy, fx * fy };
  const float wB[4] = { wz0 * ww0, fz * ww0, wz0 * fw, fz * fw };

  const float*  tbf = table + cfg.offset[s];
  const float2* __restrict__ tb  = reinterpret_cast<const float2*>(tbf);
  const float4* __restrict__ tb4 = reinterpret_cast<const float4*>(tbf);

  float a0 = 0.f, a1 = 0.f;
  if (cfg.dense[s]) {
    const uint32_t hA[4] = { x0 + y0, x1 + y0, x0 + y1, x1 + y1 };
    const uint32_t hB[4] = { z0 + u0, z1 + u0, z0 + u1, z1 + u1 };
#pragma unroll
    for (int i = 0; i < 16; ++i) {
      const uint32_t idx = hA[i & 3] + hB[i >> 2];
      const float2 v = tb[idx];
      const float w = wA[i & 3] * wB[i >> 2];
      a0 = fmaf(w, v.x, a0);
      a1 = fmaf(w, v.y, a1);
    }
  } else {
    const uint32_t msk = cfg.mask[s];
    if ((ix & 1u) == 0u) {
      // even ix: x-corner pair = {p, p^1} -> one aligned float4 each
      const uint32_t yv[2] = { y0, y1 };
      const uint32_t zw[4] = { z0 ^ u0, z1 ^ u0, z0 ^ u1, z1 ^ u1 };
#pragma unroll
      for (int j = 0; j < 8; ++j) {
        const int jy = j & 1, jz = j >> 1;
        const uint32_t p  = (x0 ^ yv[jy] ^ zw[jz]) & msk;
        const uint32_t e  = p & ~1u;
        const uint32_t sel = p & 1u;
        const float4 v = tb4[e >> 1];
        const float wlo = wA[2 * jy]     * wB[jz];
        const float whi = wA[2 * jy + 1] * wB[jz];
        const float l0 = sel ? v.z : v.x, l1 = sel ? v.w : v.y;
        const float h0 = sel ? v.x : v.z, h1 = sel ? v.y : v.w;
        a0 = fmaf(wlo, l0, fmaf(whi, h0, a0));
        a1 = fmaf(wlo, l1, fmaf(whi, h1, a1));
      }
    } else {
      const uint32_t hA[4] = { x0 ^ y0, x1 ^ y0, x0 ^ y1, x1 ^ y1 };
      const uint32_t hB[4] = { z0 ^ u0, z1 ^ u0, z0 ^ u1, z1 ^ u1 };
#pragma unroll
      for (int i = 0; i < 16; ++i) {
        const uint32_t idx = (hA[i & 3] ^ hB[i >> 2]) & msk;
        const float2 v = tb[idx];
        const float w = wA[i & 3] * wB[i >> 2];
        a0 = fmaf(w, v.x, a0);
        a1 = fmaf(w, v.y, a1);
      }
    }
  }
  v2f val = { a0, a1 };
  __builtin_nontemporal_store(val, (v2f*)&ws[(size_t)s * N + q]);
}

// ---------------- direct transpose + perm scatter ----------------
// thread = one float4 of output (2 scales x 2 feats for one query)
__global__ __launch_bounds__(TPB) void transpose_direct(
    const float2*   __restrict__ ws,
    const uint32_t* __restrict__ perm,
    float*          __restrict__ out,
    int N)
{
  const int g = blockIdx.x * TPB + threadIdx.x;
  if (g >= N * 8) return;
  const int q  = g >> 3;
  const int l8 = g & 7;
  const int s0 = l8 * 2;
  const float2 a = ws[(size_t)s0 * N + q];
  const float2 b = ws[(size_t)(s0 + 1) * N + q];
  const uint32_t pq = perm[q];
  v4f val = { a.x, a.y, b.x, b.y };
  __builtin_nontemporal_store(val, (v4f*)(out + (size_t)pq * 32 + l8 * 4));
}

// ---------------- fallback phase-2: LDS transpose (no perm) ----------------
__global__ __launch_bounds__(TPB) void transpose_kernel(
    const float2* __restrict__ ws,
    float*        __restrict__ out,
    int N)
{
  __shared__ float2 st[NSCALES][TPB + 1];
  const int t  = threadIdx.x;
  const int q  = blockIdx.x * TPB + t;
  const int ql = q < N ? q : N - 1;
#pragma unroll
  for (int s = 0; s < NSCALES; ++s)
    st[s][t] = ws[(size_t)s * N + ql];
  __syncthreads();
  const int base = blockIdx.x * (TPB * 2 * NSCALES);
#pragma unroll
  for (int it = 0; it < 8; ++it) {
    const int G  = it * 1024 + t * 4;
    const int qi = G >> 5;
    const int s0 = (G & 31) >> 1;
    if (blockIdx.x * TPB + qi < N) {
      const float2 a = st[s0][qi];
      const float2 b = st[s0 + 1][qi];
      v4f val = { a.x, a.y, b.x, b.y };
      __builtin_nontemporal_store(val, (v4f*)(out + base + G));
    }
  }
}

// ---------------- fallback: fused single-kernel (if ws tiny) ----------------
__global__ __launch_bounds__(TPB) void hashenc_fused(
    const float4* __restrict__ xyzt,
    const float*  __restrict__ table,
    float*        __restrict__ out,
    int N, Cfg cfg)
{
  __shared__ float2 st[NSCALES][TPB + 1];
  const int t  = threadIdx.x;
  const int q  = blockIdx.x * TPB + t;
  const int ql = q < N ? q : N - 1;
  const float4 c = xyzt[ql];
#pragma unroll 1
  for (int s = 0; s < NSCALES; ++s) {
    const float rx = cfg.res[s][0], ry = cfg.res[s][1];
    const float rz = cfg.res[s][2], rw = cfg.res[s][3];
    const uint32_t K0 = cfg.key[s][0], K1 = cfg.key[s][1];
    const uint32_t K2 = cfg.key[s][2], K3 = cfg.key[s][3];
    const float px = c.x * rx, py = c.y * ry, pz = c.z * rz, pw = c.w * rw;
    const float gx = floorf(px), gy = floorf(py), gz = floorf(pz), gw = floorf(pw);
    const float fx = px - gx, fy = py - gy, fz = pz - gz, fw = pw - gw;
    const uint32_t ix = (uint32_t)(int)gx, iy = (uint32_t)(int)gy;
    const uint32_t iz = (uint32_t)(int)gz, iw = (uint32_t)(int)gw;
    const uint32_t x0 = ix * K0, x1 = x0 + K0;
    const uint32_t y0 = iy * K1, y1 = y0 + K1;
    const uint32_t z0 = iz * K2, z1 = z0 + K2;
    const uint32_t u0 = iw * K3, u1 = u0 + K3;
    const float wx0 = 1.f - fx, wy0 = 1.f - fy, wz0 = 1.f - fz, ww0 = 1.f - fw;
    const float wA[4] = { wx0 * wy0, fx * wy0, wx0 * fy, fx * fy };
    const float wB[4] = { wz0 * ww0, fz * ww0, wz0 * fw, fz * fw };
    const float2* __restrict__ tb =
        reinterpret_cast<const float2*>(table + cfg.offset[s]);
    float a0 = 0.f, a1 = 0.f;
    if (cfg.dense[s]) {
      const uint32_t hA[4] = { x0 + y0, x1 + y0, x0 + y1, x1 + y1 };
      const uint32_t hB[4] = { z0 + u0, z1 + u0, z0 + u1, z1 + u1 };
#pragma unroll
      for (int i = 0; i < 16; ++i) {
        const uint32_t idx = hA[i & 3] + hB[i >> 2];
        const float2 v = tb[idx];
        const float w = wA[i & 3] * wB[i >> 2];
        a0 = fmaf(w, v.x, a0); a1 = fmaf(w, v.y, a1);
      }
    } else {
      const uint32_t msk = cfg.mask[s];
      const uint32_t hA[4] = { x0 ^ y0, x1 ^ y0, x0 ^ y1, x1 ^ y1 };
      const uint32_t hB[4] = { z0 ^ u0, z1 ^ u0, z0 ^ u1, z1 ^ u1 };
#pragma unroll
      for (int i = 0; i < 16; ++i) {
        const uint32_t idx = (hA[i & 3] ^ hB[i >> 2]) & msk;
        const float2 v = tb[idx];
        const float w = wA[i & 3] * wB[i >> 2];
        a0 = fmaf(w, v.x, a0); a1 = fmaf(w, v.y, a1);
      }
    }
    st[s][t] = make_float2(a0, a1);
  }
  __syncthreads();
  const int base = blockIdx.x * (TPB * 2 * NSCALES);
#pragma unroll
  for (int it = 0; it < 8; ++it) {
    const int G  = it * 1024 + t * 4;
    const int qi = G >> 5;
    const int s0 = (G & 31) >> 1;
    if (blockIdx.x * TPB + qi < N) {
      const float2 a = st[s0][qi];
      const float2 b = st[s0 + 1][qi];
      v4f val = { a.x, a.y, b.x, b.y };
      __builtin_nontemporal_store(val, (v4f*)(out + base + G));
    }
  }
}

// ---- host-side config, bit-exact replication of build_config() ----
static void build_cfg(Cfg& cfg)
{
  const double minr[4] = { 16.0, 16.0, 16.0, 16.0 };
  const double maxr[4] = { 256.0, 256.0, 256.0, 128.0 };
  const uint32_t primes[4] = { 1u, 2654435761u, 805459861u, 3674653429u };

  double b[4];
  for (int d = 0; d < 4; ++d)
    b[d] = ::exp((::log(maxr[d]) - ::log(minr[d])) / (double)(NSCALES - 1));

  long long total = 0;
  for (int s = 0; s < NSCALES; ++s) {
    long long res[4];
    for (int d = 0; d < 4; ++d)
      res[d] = (long long)::ceil(minr[d] * ::pow(b[d], (double)s));

    const long long raw =
        (res[0] + 1) * (res[1] + 1) * (res[2] + 1) * (res[3] + 1);
    long long p = (raw % 8 == 0) ? raw : ((raw + 7) / 8) * 8;
    if (p > 524288) p = 524288;
    const int ind = (raw <= p) ? 1 : 0;

    for (int d = 0; d < 4; ++d) cfg.res[s][d] = (float)res[d];
    if (ind) {
      cfg.key[s][0] = 1u;
      cfg.key[s][1] = (uint32_t)(res[0] + 1);
      cfg.key[s][2] = (uint32_t)((res[0] + 1) * (res[1] + 1));
      cfg.key[s][3] = (uint32_t)((res[0] + 1) * (res[1] + 1) * (res[2] + 1));
    } else {
      for (int d = 0; d < 4; ++d) cfg.key[s][d] = primes[d];
    }
    cfg.mask[s]   = (uint32_t)(p - 1);
    cfg.offset[s] = (int)total;
    cfg.dense[s]  = ind;
    total += p * 2;
  }
}

static inline size_t align_up(size_t v, size_t a) { return (v + a - 1) & ~(a - 1); }

extern "C" void kernel_launch(void* const* d_in, const int* in_sizes, int n_in,
                              void* d_out, int out_size, void* d_ws, size_t ws_size,
                              hipStream_t stream)
{
  const float* xyzt  = (const float*)d_in[0];
  const float* table = (const float*)d_in[1];
  float*       out   = (float*)d_out;
  const int N = in_sizes[0] / 4;

  Cfg cfg;
  build_cfg(cfg);

  const int qblocks = (N + TPB - 1) / TPB;

  // workspace layout
  size_t off = 0;
  const size_t perm_off = off;             off = align_up(off + (size_t)N * 4, 256);
  const size_t hist_off = off;             off = align_up(off + (size_t)BINS * 4, 256);
  const size_t cur_off  = off;             off = align_up(off + (size_t)BINS * 4, 256);
  const size_t boff_off = off;             off = align_up(off + (size_t)BINS * 4, 256);
  const size_t cs_off   = align_up(off, 16);  off = cs_off + (size_t)N * 16;
  const size_t ws_off   = align_up(off, 16);
  const size_t need_sorted = ws_off + (size_t)N * NSCALES * sizeof(float2);
  const size_t need_plain  = (size_t)N * NSCALES * sizeof(float2);

  char* wsb = (char*)d_ws;

  if (ws_size >= need_sorted) {
    uint32_t* perm = (uint32_t*)(wsb + perm_off);
    uint32_t* hist = (uint32_t*)(wsb + hist_off);
    uint32_t* cur  = (uint32_t*)(wsb + cur_off);
    uint32_t* boff = (uint32_t*)(wsb + boff_off);
    float*    csrt = (float*)(wsb + cs_off);
    float2*   ws   = (float2*)(wsb + ws_off);

    hipMemsetAsync(hist, 0, (size_t)BINS * 4, stream);
    hipMemsetAsync(cur,  0, (size_t)BINS * 4, stream);
    hipLaunchKernelGGL(hist_kernel, dim3(qblocks), dim3(TPB), 0, stream,
                       xyzt, hist, N);
    hipLaunchKernelGGL(scan_kernel, dim3(1), dim3(256), 0, stream, hist, boff);
    hipLaunchKernelGGL(scatter_kernel, dim3(qblocks), dim3(TPB), 0, stream,
                       xyzt, boff, cur, perm, csrt, N);
    hipLaunchKernelGGL(gather_kernel, dim3(qblocks, NSCALES), dim3(TPB), 0,
                       stream, csrt, table, ws, N, cfg);
    const int tblocks = (N * 8 + TPB - 1) / TPB;
    hipLaunchKernelGGL(transpose_direct, dim3(tblocks), dim3(TPB), 0, stream,
                       ws, perm, out, N);
  } else if (ws_size >= need_plain) {
    float2* ws = (float2*)d_ws;
    hipLaunchKernelGGL(gather_kernel, dim3(qblocks, NSCALES), dim3(TPB), 0,
                       stream, xyzt, table, ws, N, cfg);
    hipLaunchKernelGGL(transpose_kernel, dim3(qblocks), dim3(TPB), 0,
                       stream, ws, out, N);
  } else {
    hipLaunchKernelGGL(hashenc_fused, dim3(qblocks), dim3(TPB), 0,
                       stream, (const float4*)xyzt, table, out, N, cfg);
  }
}